// Round 13
// baseline (1935.463 us; speedup 1.0000x reference)
//
#include <hip/hip_runtime.h>

// Problem constants (from reference setup_inputs)
constexpr int B = 16;
constexpr int D = 256;
constexpr int K = 18;
constexpr int SZ = 128;
constexpr int S = SZ * SZ;      // 16384 positions per plane
constexpr int N = S / 2;        // 8192 sampled positions
constexpr int PB = 256;         // positions per block (argmin)

// ---------------------------------------------------------------------------
// Prep (identical to passing rounds 5-12): blocks 0..31 scatter mask ones
// (mask pre-zeroed by memset); blocks 32..103 compute p2 = ||proto||^2 fp64.
// ---------------------------------------------------------------------------
__global__ __launch_bounds__(256) void prep2_kernel(
    const float* __restrict__ proto,
    const int* __restrict__ idx,
    unsigned char* __restrict__ mask,
    double* __restrict__ p2) {
  const int blk = blockIdx.x;
  if (blk < 32) {
    mask[idx[blk * 256 + threadIdx.x]] = 1;   // indices are a permutation
  } else {
    const int row  = (blk - 32) * 4 + (threadIdx.x >> 6);  // 0..287 = b*K+k
    const int lane = threadIdx.x & 63;
    const float4 v = *(const float4*)(proto + (size_t)row * D + lane * 4);
    double s = (double)v.x * (double)v.x + (double)v.y * (double)v.y
             + (double)v.z * (double)v.z + (double)v.w * (double)v.w;
#pragma unroll
    for (int off = 1; off < 64; off <<= 1)
      s += __shfl_xor(s, off, 64);
    if (lane == 0) p2[row] = s;
  }
}

// Per-plane dot step: 8 positions (lo/hi float4), lane's k-eighth {e,8+e,16+e}.
#define COMPUTE_D(LO, HI, DD)                                        \
  {                                                                  \
    const double f0 = (double)LO.x, f1 = (double)LO.y;               \
    const double f2 = (double)LO.z, f3 = (double)LO.w;               \
    const double f4 = (double)HI.x, f5 = (double)HI.y;               \
    const double f6 = (double)HI.z, f7 = (double)HI.w;               \
    {                                                                \
      const double pk = spd[DD][e];                                  \
      acc0[0] += f0 * pk; acc0[1] += f1 * pk;                        \
      acc0[2] += f2 * pk; acc0[3] += f3 * pk;                        \
      acc0[4] += f4 * pk; acc0[5] += f5 * pk;                        \
      acc0[6] += f6 * pk; acc0[7] += f7 * pk;                        \
    }                                                                \
    {                                                                \
      const double pk = spd[DD][8 + e];                              \
      acc1[0] += f0 * pk; acc1[1] += f1 * pk;                        \
      acc1[2] += f2 * pk; acc1[3] += f3 * pk;                        \
      acc1[4] += f4 * pk; acc1[5] += f5 * pk;                        \
      acc1[6] += f6 * pk; acc1[7] += f7 * pk;                        \
    }                                                                \
    if (e < 2) {                                                     \
      const double pk = spd[DD][16 + e];                             \
      acc2[0] += f0 * pk; acc2[1] += f1 * pk;                        \
      acc2[2] += f2 * pk; acc2[3] += f3 * pk;                        \
      acc2[4] += f4 * pk; acc2[5] += f5 * pk;                        \
      acc2[6] += f6 * pk; acc2[7] += f7 * pk;                        \
    }                                                                \
  }

// ---------------------------------------------------------------------------
// Argmin: 8-lane groups x 8 positions x k-eighths.
//  - group g = lane>>3 owns positions gpos..gpos+7; every lane of the group
//    loads BOTH float4s (coalescer dedupes -> traffic unchanged) so all 8 f's
//    are lane-local: no shuffles in the hot loop.
//  - lane e owns k in {e, 8+e} (+{16+e} for e<2): acc = 48 VGPR (vs 72/144
//    in r10/r9) -> fits under the 128-VGPR cap WITH a 2-deep ping-pong
//    prefetch (A/B x 2 planes), fixing the measured ~1.5-loads-in-flight
//    serialization (r10: 2.5 TB/s).
//  - DS: 3 broadcast ds_read_b64 per d per wave (8 unique addrs, distinct
//    banks) -> ~31 us/CU, vs 92 (r5) / 46 (r10).
//  - occupancy: grid 1024, LDS 36 KiB -> 4 blocks/CU = 16 waves/CU (2x all
//    prior rounds). launch_bounds(256,4) caps VGPR at 128 (need ~115).
//  - numerics: fp64, d ascending 0..255 per (pos,k) -> decisions identical
//    to rounds 1-12 (absmax 0.0 each). First-min: per-lane strict < over
//    ascending own-k, then lexicographic (d2,k) shfl_xor merge = numpy.
// ---------------------------------------------------------------------------
__global__ __launch_bounds__(256, 4) void argmin_kernel(
    const float* __restrict__ assp,
    const float* __restrict__ proto,
    const double* __restrict__ p2,
    signed char* __restrict__ table) {
  __shared__ double spd[D][K];    // 36 KiB

  const int b     = blockIdx.x & 15;   // batches spread across XCDs
  const int chunk = blockIdx.x >> 4;   // 0..63
  const int tid   = threadIdx.x;
  const int lane  = tid & 63;
  const int wv    = tid >> 6;
  const int g     = lane >> 3;         // group 0..7
  const int e     = lane & 7;          // k-eighth 0..7
  const int gpos  = chunk * PB + wv * 64 + g * 8;  // first of 8 positions

  const float* pbr = proto + (size_t)b * K * D;
  for (int i = tid; i < K * D; i += 256)
    spd[i & 255][i >> 8] = (double)pbr[i];
  __syncthreads();

  const float* fin = assp + (size_t)b * D * S + gpos;

  double acc0[8], acc1[8], acc2[8];
#pragma unroll
  for (int p = 0; p < 8; ++p) { acc0[p] = 0.0; acc1[p] = 0.0; acc2[p] = 0.0; }

  // ping-pong prefetch: A/B each hold 2 planes (lo+hi float4)
  float4 Al0, Ah0, Al1, Ah1, Bl0, Bh0, Bl1, Bh1;
  Al0 = *(const float4*)(fin);
  Ah0 = *(const float4*)(fin + 4);
  Al1 = *(const float4*)(fin + (size_t)S);
  Ah1 = *(const float4*)(fin + (size_t)S + 4);

  for (int t = 0; t < 64; ++t) {
    const int d = 4 * t;
    Bl0 = *(const float4*)(fin + (size_t)(d + 2) * S);      // prefetch d+2,d+3
    Bh0 = *(const float4*)(fin + (size_t)(d + 2) * S + 4);
    Bl1 = *(const float4*)(fin + (size_t)(d + 3) * S);
    Bh1 = *(const float4*)(fin + (size_t)(d + 3) * S + 4);
    COMPUTE_D(Al0, Ah0, d)
    COMPUTE_D(Al1, Ah1, d + 1)
    if (t < 63) {                                           // prefetch d+4,d+5
      Al0 = *(const float4*)(fin + (size_t)(d + 4) * S);
      Ah0 = *(const float4*)(fin + (size_t)(d + 4) * S + 4);
      Al1 = *(const float4*)(fin + (size_t)(d + 5) * S);
      Ah1 = *(const float4*)(fin + (size_t)(d + 5) * S + 4);
    }
    COMPUTE_D(Bl0, Bh0, d + 2)
    COMPUTE_D(Bl1, Bh1, d + 3)
  }

  // ---- argmin: own k's (ascending, strict <), then lexicographic merge ----
  const double* p2b = p2 + (size_t)b * K;
  const double q0 = p2b[e];
  const double q1 = p2b[8 + e];
  const double q2 = (e < 2) ? p2b[16 + e] : 0.0;

  int kst[8];
#pragma unroll
  for (int p = 0; p < 8; ++p) {
    double bb = q0 - 2.0 * acc0[p];
    int    bk = e;
    const double d1 = q1 - 2.0 * acc1[p];
    if (d1 < bb) { bb = d1; bk = 8 + e; }
    if (e < 2) {
      const double d2v = q2 - 2.0 * acc2[p];
      if (d2v < bb) { bb = d2v; bk = 16 + e; }
    }
#pragma unroll
    for (int m = 1; m < 8; m <<= 1) {
      const double ob = __shfl_xor(bb, m, 64);
      const int    ok = __shfl_xor(bk, m, 64);
      if (ob < bb || (ob == bb && ok < bk)) { bb = ob; bk = ok; }
    }
    kst[p] = bk;   // all 8 lanes of the group agree
  }

  if (e == 0) {
    uint2 w;
    w.x = (unsigned)kst[0] | ((unsigned)kst[1] << 8) |
          ((unsigned)kst[2] << 16) | ((unsigned)kst[3] << 24);
    w.y = (unsigned)kst[4] | ((unsigned)kst[5] << 8) |
          ((unsigned)kst[6] << 16) | ((unsigned)kst[7] << 24);
    *(uint2*)(table + (size_t)b * S + gpos) = w;   // gpos % 8 == 0: aligned
  }
}

// ---------------------------------------------------------------------------
// Scatter (r5-verbatim, proven ~7.2 TB/s): one block per (b,d) plane, walked
// d-DESCENDING (L3 tail reuse). Plain stores only (nt stores broke r4).
// ---------------------------------------------------------------------------
__global__ __launch_bounds__(256) void scatter_kernel(
    const float* __restrict__ assp,
    const float* __restrict__ proto,
    const signed char* __restrict__ table,
    const unsigned char* __restrict__ mask,
    float* __restrict__ out) {
  const int d  = 255 - (blockIdx.x >> 4);   // d descending across all b
  const int b  = blockIdx.x & 15;
  const int bd = b * D + d;

  __shared__ float sp[K];
  if (threadIdx.x < K)
    sp[threadIdx.x] = proto[((size_t)b * K + threadIdx.x) * D + d];
  __syncthreads();

  const signed char* tb = table + (size_t)b * S;
  const float4* in4 = (const float4*)(assp + (size_t)bd * S);
  float4* out4 = (float4*)(out + (size_t)bd * S);

#pragma unroll
  for (int it = 0; it < S / 4 / 256; ++it) {   // 16 iterations
    const int i = it * 256 + threadIdx.x;      // float4 index within plane
    char4 t, m;
    *(int*)&t = ((const int*)tb)[i];
    *(int*)&m = ((const int*)mask)[i];
    float4 v = in4[i];
    if (m.x) v.x = sp[(int)t.x];
    if (m.y) v.y = sp[(int)t.y];
    if (m.z) v.z = sp[(int)t.z];
    if (m.w) v.w = sp[(int)t.w];
    out4[i] = v;
  }
}

extern "C" void kernel_launch(void* const* d_in, const int* in_sizes, int n_in,
                              void* d_out, int out_size, void* d_ws, size_t ws_size,
                              hipStream_t stream) {
  const float* assp  = (const float*)d_in[0];
  const float* proto = (const float*)d_in[1];
  const int*   idx   = (const int*)d_in[2];
  float* out = (float*)d_out;

  // ws layout: [table: B*S bytes][mask: S bytes][p2: B*K doubles]
  signed char*   table = (signed char*)d_ws;
  unsigned char* mask  = (unsigned char*)d_ws + (size_t)B * S;
  double*        p2    = (double*)((char*)d_ws + (size_t)B * S + S);

  hipMemsetAsync(mask, 0, S, stream);   // 16 KiB
  prep2_kernel<<<104, 256, 0, stream>>>(proto, idx, mask, p2);
  argmin_kernel<<<B * (S / PB), 256, 0, stream>>>(assp, proto, p2, table);
  scatter_kernel<<<B * D, 256, 0, stream>>>(assp, proto, table, mask, out);
}